// Round 1
// baseline (927.187 us; speedup 1.0000x reference)
//
#include <hip/hip_runtime.h>

#define NN 100000
#define NE 1600000
// IN_FEAT=128, N_HEADS=8, OUT_FEAT=16, H*F=128

// ---------------- Kernel 1: proj = x @ W  ([NN,128] x [128,128]) ----------------
__global__ __launch_bounds__(256) void gemm_kernel(const float* __restrict__ x,
                                                   const float* __restrict__ W,
                                                   float* __restrict__ proj) {
    __shared__ float sX[64][32];
    __shared__ float sW[32][128];
    const int t = threadIdx.x;
    const int n0 = blockIdx.x * 64;
    const int c0 = (t & 31) * 4;   // output column base (0..124)
    const int r0 = t >> 5;         // row group 0..7
    float acc[8][4];
#pragma unroll
    for (int i = 0; i < 8; i++)
#pragma unroll
        for (int j = 0; j < 4; j++) acc[i][j] = 0.f;

    for (int kt = 0; kt < 128; kt += 32) {
        // stage X tile: 64x32 = 512 float4
#pragma unroll
        for (int p = 0; p < 2; p++) {
            int idx = t + p * 256;          // 0..511
            int r = idx >> 3;
            int kk = idx & 7;
            float4 v = make_float4(0.f, 0.f, 0.f, 0.f);
            int n = n0 + r;
            if (n < NN) v = *reinterpret_cast<const float4*>(&x[(size_t)n * 128 + kt + kk * 4]);
            *reinterpret_cast<float4*>(&sX[r][kk * 4]) = v;
        }
        // stage W tile: 32x128 = 1024 float4
#pragma unroll
        for (int p = 0; p < 4; p++) {
            int idx = t + p * 256;          // 0..1023
            int kr = idx >> 5;
            int c4 = idx & 31;
            float4 v = *reinterpret_cast<const float4*>(&W[(size_t)(kt + kr) * 128 + c4 * 4]);
            *reinterpret_cast<float4*>(&sW[kr][c4 * 4]) = v;
        }
        __syncthreads();
#pragma unroll
        for (int k = 0; k < 32; k++) {
            float4 wv = *reinterpret_cast<const float4*>(&sW[k][c0]);
#pragma unroll
            for (int i = 0; i < 8; i++) {
                float xv = sX[r0 + 8 * i][k];
                acc[i][0] += xv * wv.x;
                acc[i][1] += xv * wv.y;
                acc[i][2] += xv * wv.z;
                acc[i][3] += xv * wv.w;
            }
        }
        __syncthreads();
    }
#pragma unroll
    for (int i = 0; i < 8; i++) {
        int n = n0 + r0 + 8 * i;
        if (n < NN) {
            float4 v = make_float4(acc[i][0], acc[i][1], acc[i][2], acc[i][3]);
            *reinterpret_cast<float4*>(&proj[(size_t)n * 128 + c0]) = v;
        }
    }
}

// ---------------- Kernel 2: s_src/s_tgt = einsum('nhf,hf->nh') ----------------
__global__ __launch_bounds__(256) void score_kernel(const float* __restrict__ proj,
                                                    const float* __restrict__ a_src,
                                                    const float* __restrict__ a_tgt,
                                                    float* __restrict__ s_src,
                                                    float* __restrict__ s_tgt) {
    const int t = threadIdx.x;
    const int lane128 = t & 127;               // h*16+f
    const int node = blockIdx.x * 2 + (t >> 7);
    if (node >= NN) return;
    float p = proj[(size_t)node * 128 + lane128];
    float vs = p * a_src[lane128];
    float vt = p * a_tgt[lane128];
#pragma unroll
    for (int m = 1; m < 16; m <<= 1) {
        vs += __shfl_xor(vs, m, 64);
        vt += __shfl_xor(vt, m, 64);
    }
    if ((lane128 & 15) == 0) {
        int h = lane128 >> 4;
        s_src[node * 8 + h] = vs;
        s_tgt[node * 8 + h] = vt;
    }
}

// ---------------- Kernel 3: per-edge exp(leaky) -> denom (segment sum) ----------------
__global__ __launch_bounds__(256) void denom_kernel(const int* __restrict__ src,
                                                    const int* __restrict__ tgt,
                                                    const float* __restrict__ s_src,
                                                    const float* __restrict__ s_tgt,
                                                    float* __restrict__ denom) {
    int e = blockIdx.x * blockDim.x + threadIdx.x;
    if (e >= NE) return;
    int s = src[e], t = tgt[e];
    float4 a0 = *reinterpret_cast<const float4*>(&s_src[(size_t)s * 8]);
    float4 a1 = *reinterpret_cast<const float4*>(&s_src[(size_t)s * 8 + 4]);
    float4 b0 = *reinterpret_cast<const float4*>(&s_tgt[(size_t)t * 8]);
    float4 b1 = *reinterpret_cast<const float4*>(&s_tgt[(size_t)t * 8 + 4]);
    float eh[8] = {a0.x + b0.x, a0.y + b0.y, a0.z + b0.z, a0.w + b0.w,
                   a1.x + b1.x, a1.y + b1.y, a1.z + b1.z, a1.w + b1.w};
#pragma unroll
    for (int h = 0; h < 8; h++) {
        float v = eh[h];
        v = v >= 0.f ? v : 0.2f * v;
        atomicAdd(&denom[(size_t)t * 8 + h], expf(v));
    }
}

// ---------------- Kernel 4: per-edge alpha, head-reduced message, scatter-add ----------------
__global__ __launch_bounds__(256) void aggregate_kernel(const int* __restrict__ src,
                                                        const int* __restrict__ tgt,
                                                        const float* __restrict__ s_src,
                                                        const float* __restrict__ s_tgt,
                                                        const float* __restrict__ denom,
                                                        const float* __restrict__ proj,
                                                        float* __restrict__ out_acc) {
    int gid = blockIdx.x * blockDim.x + threadIdx.x;
    int e = gid >> 4;
    int lane = gid & 15;   // output feature f
    if (e >= NE) return;
    int s = src[e], t = tgt[e];
    int h = lane & 7;
    float eh = s_src[(size_t)s * 8 + h] + s_tgt[(size_t)t * 8 + h];
    eh = eh >= 0.f ? eh : 0.2f * eh;
    float ex = expf(eh);
    float alpha = ex / (denom[(size_t)t * 8 + h] + 1e-16f);
    const float* prow = &proj[(size_t)s * 128];
    float m = 0.f;
#pragma unroll
    for (int hh = 0; hh < 8; hh++) {
        float a = __shfl(alpha, hh, 16);   // alpha for head hh within this 16-lane group
        m += a * prow[hh * 16 + lane];
    }
    atomicAdd(&out_acc[(size_t)t * 16 + lane], m * 0.125f);
}

// ---------------- Kernel 5: bias + softmax over 16 features ----------------
__global__ __launch_bounds__(256) void softmax_kernel(const float* __restrict__ out_acc,
                                                      const float* __restrict__ bias,
                                                      float* __restrict__ out) {
    int gid = blockIdx.x * blockDim.x + threadIdx.x;
    int n = gid >> 4;
    int lane = gid & 15;
    if (n >= NN) return;
    float v = out_acc[(size_t)n * 16 + lane] + bias[lane];
    float mx = v;
#pragma unroll
    for (int m = 1; m < 16; m <<= 1) mx = fmaxf(mx, __shfl_xor(mx, m, 64));
    float ex = expf(v - mx);
    float sum = ex;
#pragma unroll
    for (int m = 1; m < 16; m <<= 1) sum += __shfl_xor(sum, m, 64);
    out[(size_t)n * 16 + lane] = ex / sum;
}

extern "C" void kernel_launch(void* const* d_in, const int* in_sizes, int n_in,
                              void* d_out, int out_size, void* d_ws, size_t ws_size,
                              hipStream_t stream) {
    const float* x     = (const float*)d_in[0];
    const int*   ei    = (const int*)d_in[1];
    const float* W     = (const float*)d_in[2];
    const float* a_src = (const float*)d_in[3];
    const float* a_tgt = (const float*)d_in[4];
    const float* bias  = (const float*)d_in[5];
    float* out = (float*)d_out;

    const int* src = ei;            // edge_index[0]
    const int* tgt = ei + NE;       // edge_index[1]

    char* ws = (char*)d_ws;
    size_t off = 0;
    auto alloc = [&](size_t bytes) {
        char* p = ws + off;
        off += (bytes + 255) & ~(size_t)255;
        return p;
    };
    float* proj    = (float*)alloc((size_t)NN * 128 * 4);  // 51.2 MB
    float* s_src   = (float*)alloc((size_t)NN * 8 * 4);
    float* s_tgt   = (float*)alloc((size_t)NN * 8 * 4);
    float* denom   = (float*)alloc((size_t)NN * 8 * 4);
    float* out_acc = (float*)alloc((size_t)NN * 16 * 4);

    // zero accumulators every call (harness does not re-poison between replays)
    hipMemsetAsync(denom, 0, (size_t)NN * 8 * 4, stream);
    hipMemsetAsync(out_acc, 0, (size_t)NN * 16 * 4, stream);

    gemm_kernel<<<(NN + 63) / 64, 256, 0, stream>>>(x, W, proj);
    score_kernel<<<(NN + 1) / 2, 256, 0, stream>>>(proj, a_src, a_tgt, s_src, s_tgt);
    denom_kernel<<<(NE + 255) / 256, 256, 0, stream>>>(src, tgt, s_src, s_tgt, denom);
    aggregate_kernel<<<((size_t)NE * 16 + 255) / 256, 256, 0, stream>>>(src, tgt, s_src, s_tgt,
                                                                        denom, proj, out_acc);
    softmax_kernel<<<(NN * 16 + 255) / 256, 256, 0, stream>>>(out_acc, bias, out);
}

// Round 6
// 360.385 us; speedup vs baseline: 2.5728x; 2.5728x over previous
//
#include <hip/hip_runtime.h>

#define NN 100000
#define NE 1600000
// IN_FEAT=128, N_HEADS=8, OUT_FEAT=16, H*F=128

// ---------------- Kernel 1: proj = x @ W  ([NN,128] x [128,128]) ----------------
__global__ __launch_bounds__(256) void gemm_kernel(const float* __restrict__ x,
                                                   const float* __restrict__ W,
                                                   float* __restrict__ proj) {
    __shared__ float sX[64][32];
    __shared__ float sW[32][128];
    const int t = threadIdx.x;
    const int n0 = blockIdx.x * 64;
    const int c0 = (t & 31) * 4;   // output column base (0..124)
    const int r0 = t >> 5;         // row group 0..7
    float acc[8][4];
#pragma unroll
    for (int i = 0; i < 8; i++)
#pragma unroll
        for (int j = 0; j < 4; j++) acc[i][j] = 0.f;

    for (int kt = 0; kt < 128; kt += 32) {
        // stage X tile: 64x32 = 512 float4
#pragma unroll
        for (int p = 0; p < 2; p++) {
            int idx = t + p * 256;          // 0..511
            int r = idx >> 3;
            int kk = idx & 7;
            float4 v = make_float4(0.f, 0.f, 0.f, 0.f);
            int n = n0 + r;
            if (n < NN) v = *reinterpret_cast<const float4*>(&x[(size_t)n * 128 + kt + kk * 4]);
            *reinterpret_cast<float4*>(&sX[r][kk * 4]) = v;
        }
        // stage W tile: 32x128 = 1024 float4
#pragma unroll
        for (int p = 0; p < 4; p++) {
            int idx = t + p * 256;          // 0..1023
            int kr = idx >> 5;
            int c4 = idx & 31;
            float4 v = *reinterpret_cast<const float4*>(&W[(size_t)(kt + kr) * 128 + c4 * 4]);
            *reinterpret_cast<float4*>(&sW[kr][c4 * 4]) = v;
        }
        __syncthreads();
#pragma unroll
        for (int k = 0; k < 32; k++) {
            float4 wv = *reinterpret_cast<const float4*>(&sW[k][c0]);
#pragma unroll
            for (int i = 0; i < 8; i++) {
                float xv = sX[r0 + 8 * i][k];
                acc[i][0] += xv * wv.x;
                acc[i][1] += xv * wv.y;
                acc[i][2] += xv * wv.z;
                acc[i][3] += xv * wv.w;
            }
        }
        __syncthreads();
    }
#pragma unroll
    for (int i = 0; i < 8; i++) {
        int n = n0 + r0 + 8 * i;
        if (n < NN) {
            float4 v = make_float4(acc[i][0], acc[i][1], acc[i][2], acc[i][3]);
            *reinterpret_cast<float4*>(&proj[(size_t)n * 128 + c0]) = v;
        }
    }
}

// ---------------- Kernel 2: s_src/s_tgt = einsum('nhf,hf->nh') ----------------
__global__ __launch_bounds__(256) void score_kernel(const float* __restrict__ proj,
                                                    const float* __restrict__ a_src,
                                                    const float* __restrict__ a_tgt,
                                                    float* __restrict__ s_src,
                                                    float* __restrict__ s_tgt) {
    const int t = threadIdx.x;
    const int lane128 = t & 127;               // h*16+f
    const int node = blockIdx.x * 2 + (t >> 7);
    if (node >= NN) return;
    float p = proj[(size_t)node * 128 + lane128];
    float vs = p * a_src[lane128];
    float vt = p * a_tgt[lane128];
#pragma unroll
    for (int m = 1; m < 16; m <<= 1) {
        vs += __shfl_xor(vs, m, 64);
        vt += __shfl_xor(vt, m, 64);
    }
    if ((lane128 & 15) == 0) {
        int h = lane128 >> 4;
        s_src[node * 8 + h] = vs;
        s_tgt[node * 8 + h] = vt;
    }
}

// ---------------- Kernel 3: per-(edge,head) exp(leaky) -> denom (segment sum) ----------------
// One lane per (edge, head): 8 consecutive lanes -> 8 consecutive denom addresses,
// so each wave issues coalesced atomics (few L2 lines/instr) instead of 8 divergent ones.
__global__ __launch_bounds__(256) void denom_kernel(const int* __restrict__ src,
                                                    const int* __restrict__ tgt,
                                                    const float* __restrict__ s_src,
                                                    const float* __restrict__ s_tgt,
                                                    float* __restrict__ denom) {
    int gid = blockIdx.x * blockDim.x + threadIdx.x;
    int e = gid >> 3;
    if (e >= NE) return;
    int h = gid & 7;
    int s = src[e], t = tgt[e];
    float v = s_src[(size_t)s * 8 + h] + s_tgt[(size_t)t * 8 + h];
    v = v >= 0.f ? v : 0.2f * v;
    atomicAdd(&denom[(size_t)t * 8 + h], expf(v));
}

// ---------------- Kernel 4: per-edge alpha, head-reduced message, scatter-add ----------------
__global__ __launch_bounds__(256) void aggregate_kernel(const int* __restrict__ src,
                                                        const int* __restrict__ tgt,
                                                        const float* __restrict__ s_src,
                                                        const float* __restrict__ s_tgt,
                                                        const float* __restrict__ denom,
                                                        const float* __restrict__ proj,
                                                        float* __restrict__ out_acc) {
    int gid = blockIdx.x * blockDim.x + threadIdx.x;
    int e = gid >> 4;
    int lane = gid & 15;   // output feature f
    if (e >= NE) return;
    int s = src[e], t = tgt[e];
    int h = lane & 7;
    float eh = s_src[(size_t)s * 8 + h] + s_tgt[(size_t)t * 8 + h];
    eh = eh >= 0.f ? eh : 0.2f * eh;
    float ex = expf(eh);
    float alpha = ex / (denom[(size_t)t * 8 + h] + 1e-16f);
    const float* prow = &proj[(size_t)s * 128];
    float m = 0.f;
#pragma unroll
    for (int hh = 0; hh < 8; hh++) {
        float a = __shfl(alpha, hh, 16);   // alpha for head hh within this 16-lane group
        m += a * prow[hh * 16 + lane];
    }
    atomicAdd(&out_acc[(size_t)t * 16 + lane], m * 0.125f);
}

// ---------------- Kernel 5: bias + softmax over 16 features ----------------
__global__ __launch_bounds__(256) void softmax_kernel(const float* __restrict__ out_acc,
                                                      const float* __restrict__ bias,
                                                      float* __restrict__ out) {
    int gid = blockIdx.x * blockDim.x + threadIdx.x;
    int n = gid >> 4;
    int lane = gid & 15;
    if (n >= NN) return;
    float v = out_acc[(size_t)n * 16 + lane] + bias[lane];
    float mx = v;
#pragma unroll
    for (int m = 1; m < 16; m <<= 1) mx = fmaxf(mx, __shfl_xor(mx, m, 64));
    float ex = expf(v - mx);
    float sum = ex;
#pragma unroll
    for (int m = 1; m < 16; m <<= 1) sum += __shfl_xor(sum, m, 64);
    out[(size_t)n * 16 + lane] = ex / sum;
}

extern "C" void kernel_launch(void* const* d_in, const int* in_sizes, int n_in,
                              void* d_out, int out_size, void* d_ws, size_t ws_size,
                              hipStream_t stream) {
    const float* x     = (const float*)d_in[0];
    const int*   ei    = (const int*)d_in[1];
    const float* W     = (const float*)d_in[2];
    const float* a_src = (const float*)d_in[3];
    const float* a_tgt = (const float*)d_in[4];
    const float* bias  = (const float*)d_in[5];
    float* out = (float*)d_out;

    const int* src = ei;            // edge_index[0]
    const int* tgt = ei + NE;       // edge_index[1]

    char* ws = (char*)d_ws;
    size_t off = 0;
    auto alloc = [&](size_t bytes) {
        char* p = ws + off;
        off += (bytes + 255) & ~(size_t)255;
        return p;
    };
    float* proj    = (float*)alloc((size_t)NN * 128 * 4);  // 51.2 MB
    float* s_src   = (float*)alloc((size_t)NN * 8 * 4);
    float* s_tgt   = (float*)alloc((size_t)NN * 8 * 4);
    float* denom   = (float*)alloc((size_t)NN * 8 * 4);
    float* out_acc = (float*)alloc((size_t)NN * 16 * 4);

    // zero accumulators every call (harness does not re-poison between replays)
    hipMemsetAsync(denom, 0, (size_t)NN * 8 * 4, stream);
    hipMemsetAsync(out_acc, 0, (size_t)NN * 16 * 4, stream);

    gemm_kernel<<<(NN + 63) / 64, 256, 0, stream>>>(x, W, proj);
    score_kernel<<<(NN + 1) / 2, 256, 0, stream>>>(proj, a_src, a_tgt, s_src, s_tgt);
    denom_kernel<<<((size_t)NE * 8 + 255) / 256, 256, 0, stream>>>(src, tgt, s_src, s_tgt, denom);
    aggregate_kernel<<<((size_t)NE * 16 + 255) / 256, 256, 0, stream>>>(src, tgt, s_src, s_tgt,
                                                                        denom, proj, out_acc);
    softmax_kernel<<<(NN * 16 + 255) / 256, 256, 0, stream>>>(out_acc, bias, out);
}

// Round 7
// 303.365 us; speedup vs baseline: 3.0563x; 1.1880x over previous
//
#include <hip/hip_runtime.h>

#define NN 100000
#define NE 1600000
// IN_FEAT=128, N_HEADS=8, OUT_FEAT=16, H*F=128

static __device__ __forceinline__ unsigned short f32_to_bf16_rne(float x) {
    unsigned int u = __float_as_uint(x);
    u += 0x7fff + ((u >> 16) & 1);   // round-to-nearest-even
    return (unsigned short)(u >> 16);
}
static __device__ __forceinline__ float bf16_to_f32(unsigned int bits16) {
    return __uint_as_float(bits16 << 16);
}

// ---------------- Kernel 1: proj = x @ W  ([NN,128] x [128,128]) ----------------
// Also emits projT: bf16, feature-major per node: projT[n*128 + f*8 + h].
__global__ __launch_bounds__(256) void gemm_kernel(const float* __restrict__ x,
                                                   const float* __restrict__ W,
                                                   float* __restrict__ proj,
                                                   unsigned short* __restrict__ projT) {
    __shared__ float sX[64][32];
    __shared__ float sW[32][128];
    const int t = threadIdx.x;
    const int n0 = blockIdx.x * 64;
    const int c0 = (t & 31) * 4;   // output column base (0..124); head h=c0>>4, feat f0=c0&15
    const int r0 = t >> 5;         // row group 0..7
    float acc[8][4];
#pragma unroll
    for (int i = 0; i < 8; i++)
#pragma unroll
        for (int j = 0; j < 4; j++) acc[i][j] = 0.f;

    for (int kt = 0; kt < 128; kt += 32) {
#pragma unroll
        for (int p = 0; p < 2; p++) {
            int idx = t + p * 256;          // 0..511
            int r = idx >> 3;
            int kk = idx & 7;
            float4 v = make_float4(0.f, 0.f, 0.f, 0.f);
            int n = n0 + r;
            if (n < NN) v = *reinterpret_cast<const float4*>(&x[(size_t)n * 128 + kt + kk * 4]);
            *reinterpret_cast<float4*>(&sX[r][kk * 4]) = v;
        }
#pragma unroll
        for (int p = 0; p < 4; p++) {
            int idx = t + p * 256;          // 0..1023
            int kr = idx >> 5;
            int c4 = idx & 31;
            float4 v = *reinterpret_cast<const float4*>(&W[(size_t)(kt + kr) * 128 + c4 * 4]);
            *reinterpret_cast<float4*>(&sW[kr][c4 * 4]) = v;
        }
        __syncthreads();
#pragma unroll
        for (int k = 0; k < 32; k++) {
            float4 wv = *reinterpret_cast<const float4*>(&sW[k][c0]);
#pragma unroll
            for (int i = 0; i < 8; i++) {
                float xv = sX[r0 + 8 * i][k];
                acc[i][0] += xv * wv.x;
                acc[i][1] += xv * wv.y;
                acc[i][2] += xv * wv.z;
                acc[i][3] += xv * wv.w;
            }
        }
        __syncthreads();
    }
    const int h  = c0 >> 4;   // head of this thread's 4 columns
    const int f0 = c0 & 15;   // first feature
#pragma unroll
    for (int i = 0; i < 8; i++) {
        int n = n0 + r0 + 8 * i;
        if (n < NN) {
            float4 v = make_float4(acc[i][0], acc[i][1], acc[i][2], acc[i][3]);
            *reinterpret_cast<float4*>(&proj[(size_t)n * 128 + c0]) = v;
            unsigned short* pT = &projT[(size_t)n * 128];
#pragma unroll
            for (int j = 0; j < 4; j++) pT[(f0 + j) * 8 + h] = f32_to_bf16_rne(acc[i][j]);
        }
    }
}

// ---------------- Kernel 2: s_src/s_tgt = einsum('nhf,hf->nh') ----------------
__global__ __launch_bounds__(256) void score_kernel(const float* __restrict__ proj,
                                                    const float* __restrict__ a_src,
                                                    const float* __restrict__ a_tgt,
                                                    float* __restrict__ s_src,
                                                    float* __restrict__ s_tgt) {
    const int t = threadIdx.x;
    const int lane128 = t & 127;               // h*16+f
    const int node = blockIdx.x * 2 + (t >> 7);
    if (node >= NN) return;
    float p = proj[(size_t)node * 128 + lane128];
    float vs = p * a_src[lane128];
    float vt = p * a_tgt[lane128];
#pragma unroll
    for (int m = 1; m < 16; m <<= 1) {
        vs += __shfl_xor(vs, m, 64);
        vt += __shfl_xor(vt, m, 64);
    }
    if ((lane128 & 15) == 0) {
        int h = lane128 >> 4;
        s_src[node * 8 + h] = vs;
        s_tgt[node * 8 + h] = vt;
    }
}

// ---------------- Kernel 3: per-(edge,head) exp(leaky) -> denom (segment sum) ----------------
__global__ __launch_bounds__(256) void denom_kernel(const int* __restrict__ src,
                                                    const int* __restrict__ tgt,
                                                    const float* __restrict__ s_src,
                                                    const float* __restrict__ s_tgt,
                                                    float* __restrict__ denom) {
    int gid = blockIdx.x * blockDim.x + threadIdx.x;
    int e = gid >> 3;
    if (e >= NE) return;
    int h = gid & 7;
    int s = src[e], t = tgt[e];
    float v = s_src[(size_t)s * 8 + h] + s_tgt[(size_t)t * 8 + h];
    v = v >= 0.f ? v : 0.2f * v;
    atomicAdd(&denom[(size_t)t * 8 + h], expf(v));
}

// ---------------- Kernel 4: per-edge alpha, head-reduced message, scatter-add ----------------
// 16 lanes per edge (lane = feature f). Each lane loads all 8 heads of feature f
// from the transposed bf16 proj in one 16B load -> 256 B/edge, fully coalesced.
__global__ __launch_bounds__(256) void aggregate_kernel(const int* __restrict__ src,
                                                        const int* __restrict__ tgt,
                                                        const float* __restrict__ s_src,
                                                        const float* __restrict__ s_tgt,
                                                        const float* __restrict__ denom,
                                                        const unsigned short* __restrict__ projT,
                                                        float* __restrict__ out_acc) {
    int gid = blockIdx.x * blockDim.x + threadIdx.x;
    int e = gid >> 4;
    int lane = gid & 15;   // output feature f
    if (e >= NE) return;
    int s = src[e], t = tgt[e];
    int h = lane & 7;
    float eh = s_src[(size_t)s * 8 + h] + s_tgt[(size_t)t * 8 + h];
    eh = eh >= 0.f ? eh : 0.2f * eh;
    float ex = expf(eh);
    float alpha = ex / (denom[(size_t)t * 8 + h] + 1e-16f);
    // gather 8 heads at feature 'lane': 16 bytes
    uint4 v = *reinterpret_cast<const uint4*>(&projT[(size_t)s * 128 + lane * 8]);
    float p0 = bf16_to_f32(v.x & 0xffffu), p1 = bf16_to_f32(v.x >> 16);
    float p2 = bf16_to_f32(v.y & 0xffffu), p3 = bf16_to_f32(v.y >> 16);
    float p4 = bf16_to_f32(v.z & 0xffffu), p5 = bf16_to_f32(v.z >> 16);
    float p6 = bf16_to_f32(v.w & 0xffffu), p7 = bf16_to_f32(v.w >> 16);
    float m = 0.f;
    m += __shfl(alpha, 0, 16) * p0;
    m += __shfl(alpha, 1, 16) * p1;
    m += __shfl(alpha, 2, 16) * p2;
    m += __shfl(alpha, 3, 16) * p3;
    m += __shfl(alpha, 4, 16) * p4;
    m += __shfl(alpha, 5, 16) * p5;
    m += __shfl(alpha, 6, 16) * p6;
    m += __shfl(alpha, 7, 16) * p7;
    atomicAdd(&out_acc[(size_t)t * 16 + lane], m * 0.125f);
}

// ---------------- Kernel 5: bias + softmax over 16 features ----------------
__global__ __launch_bounds__(256) void softmax_kernel(const float* __restrict__ out_acc,
                                                      const float* __restrict__ bias,
                                                      float* __restrict__ out) {
    int gid = blockIdx.x * blockDim.x + threadIdx.x;
    int n = gid >> 4;
    int lane = gid & 15;
    if (n >= NN) return;
    float v = out_acc[(size_t)n * 16 + lane] + bias[lane];
    float mx = v;
#pragma unroll
    for (int m = 1; m < 16; m <<= 1) mx = fmaxf(mx, __shfl_xor(mx, m, 64));
    float ex = expf(v - mx);
    float sum = ex;
#pragma unroll
    for (int m = 1; m < 16; m <<= 1) sum += __shfl_xor(sum, m, 64);
    out[(size_t)n * 16 + lane] = ex / sum;
}

extern "C" void kernel_launch(void* const* d_in, const int* in_sizes, int n_in,
                              void* d_out, int out_size, void* d_ws, size_t ws_size,
                              hipStream_t stream) {
    const float* x     = (const float*)d_in[0];
    const int*   ei    = (const int*)d_in[1];
    const float* W     = (const float*)d_in[2];
    const float* a_src = (const float*)d_in[3];
    const float* a_tgt = (const float*)d_in[4];
    const float* bias  = (const float*)d_in[5];
    float* out = (float*)d_out;

    const int* src = ei;            // edge_index[0]
    const int* tgt = ei + NE;       // edge_index[1]

    char* ws = (char*)d_ws;
    size_t off = 0;
    auto alloc = [&](size_t bytes) {
        char* p = ws + off;
        off += (bytes + 255) & ~(size_t)255;
        return p;
    };
    float*          proj    = (float*)alloc((size_t)NN * 128 * 4);          // 51.2 MB
    unsigned short* projT   = (unsigned short*)alloc((size_t)NN * 128 * 2); // 25.6 MB bf16, f-major
    float*          s_src   = (float*)alloc((size_t)NN * 8 * 4);
    float*          s_tgt   = (float*)alloc((size_t)NN * 8 * 4);
    float*          denom   = (float*)alloc((size_t)NN * 8 * 4);
    float*          out_acc = (float*)alloc((size_t)NN * 16 * 4);

    // zero accumulators every call (harness does not re-poison between replays)
    hipMemsetAsync(denom, 0, (size_t)NN * 8 * 4, stream);
    hipMemsetAsync(out_acc, 0, (size_t)NN * 16 * 4, stream);

    gemm_kernel<<<(NN + 63) / 64, 256, 0, stream>>>(x, W, proj, projT);
    score_kernel<<<(NN + 1) / 2, 256, 0, stream>>>(proj, a_src, a_tgt, s_src, s_tgt);
    denom_kernel<<<((size_t)NE * 8 + 255) / 256, 256, 0, stream>>>(src, tgt, s_src, s_tgt, denom);
    aggregate_kernel<<<((size_t)NE * 16 + 255) / 256, 256, 0, stream>>>(src, tgt, s_src, s_tgt,
                                                                        denom, projT, out_acc);
    softmax_kernel<<<(NN * 16 + 255) / 256, 256, 0, stream>>>(out_acc, bias, out);
}

// Round 8
// 269.905 us; speedup vs baseline: 3.4352x; 1.1240x over previous
//
#include <hip/hip_runtime.h>

#define NN 100000
#define NE 1600000
// IN_FEAT=128, N_HEADS=8, OUT_FEAT=16, H*F=128

static __device__ __forceinline__ unsigned short f32_to_bf16_rne(float x) {
    unsigned int u = __float_as_uint(x);
    u += 0x7fff + ((u >> 16) & 1);   // round-to-nearest-even
    return (unsigned short)(u >> 16);
}
static __device__ __forceinline__ float bf16_to_f32(unsigned int bits16) {
    return __uint_as_float(bits16 << 16);
}

// ---------------- Kernel 1: fused proj-GEMM + attention scores ----------------
// proj = x @ W (f32 accum, [64 x 128] tile per block).
// Outputs: projT bf16 feature-major (projT[n*128 + f*8 + h]),
//          s_src[n*8+h] (f32), pack[n*16+h] = s_tgt (pack[n*16+8+h] = denom, filled later).
// Scores are computed from the f32 accumulator registers (full precision), so the
// f32 proj array is never materialized.
__global__ __launch_bounds__(256) void gemm_score_kernel(const float* __restrict__ x,
                                                         const float* __restrict__ W,
                                                         const float* __restrict__ a_src,
                                                         const float* __restrict__ a_tgt,
                                                         unsigned short* __restrict__ projT,
                                                         float* __restrict__ s_src,
                                                         float* __restrict__ pack) {
    __shared__ float sXT[32][68];   // k-major, padded: conflict-light b128 broadcast reads
    __shared__ float sW[32][128];
    const int t = threadIdx.x;
    const int n0 = blockIdx.x * 64;
    const int c0 = (t & 31) * 4;    // output column base; head h=c0>>4, feat f0=c0&15
    const int r0 = t >> 5;          // row group 0..7 -> rows r0*8 .. r0*8+7
    float acc[8][4];
#pragma unroll
    for (int i = 0; i < 8; i++)
#pragma unroll
        for (int j = 0; j < 4; j++) acc[i][j] = 0.f;

    for (int kt = 0; kt < 128; kt += 32) {
        // stage X tile transposed: sXT[k][r]
#pragma unroll
        for (int p = 0; p < 2; p++) {
            int idx = t + p * 256;          // 0..511
            int r = idx >> 3;
            int kk = idx & 7;
            float4 v = make_float4(0.f, 0.f, 0.f, 0.f);
            int n = n0 + r;
            if (n < NN) v = *reinterpret_cast<const float4*>(&x[(size_t)n * 128 + kt + kk * 4]);
            sXT[kk * 4 + 0][r] = v.x;
            sXT[kk * 4 + 1][r] = v.y;
            sXT[kk * 4 + 2][r] = v.z;
            sXT[kk * 4 + 3][r] = v.w;
        }
        // stage W tile: 32x128
#pragma unroll
        for (int p = 0; p < 4; p++) {
            int idx = t + p * 256;          // 0..1023
            int kr = idx >> 5;
            int c4 = idx & 31;
            float4 v = *reinterpret_cast<const float4*>(&W[(size_t)(kt + kr) * 128 + c4 * 4]);
            *reinterpret_cast<float4*>(&sW[kr][c4 * 4]) = v;
        }
        __syncthreads();
#pragma unroll
        for (int k = 0; k < 32; k++) {
            float4 xa = *reinterpret_cast<const float4*>(&sXT[k][r0 * 8]);
            float4 xb = *reinterpret_cast<const float4*>(&sXT[k][r0 * 8 + 4]);
            float4 wv = *reinterpret_cast<const float4*>(&sW[k][c0]);
            float xs[8] = {xa.x, xa.y, xa.z, xa.w, xb.x, xb.y, xb.z, xb.w};
#pragma unroll
            for (int i = 0; i < 8; i++) {
                acc[i][0] += xs[i] * wv.x;
                acc[i][1] += xs[i] * wv.y;
                acc[i][2] += xs[i] * wv.z;
                acc[i][3] += xs[i] * wv.w;
            }
        }
        __syncthreads();
    }
    const int h  = c0 >> 4;        // head of this thread's 4 columns
    const int f0 = c0 & 15;        // first feature
    const float aS0 = a_src[c0], aS1 = a_src[c0 + 1], aS2 = a_src[c0 + 2], aS3 = a_src[c0 + 3];
    const float aT0 = a_tgt[c0], aT1 = a_tgt[c0 + 1], aT2 = a_tgt[c0 + 2], aT3 = a_tgt[c0 + 3];
#pragma unroll
    for (int i = 0; i < 8; i++) {
        int n = n0 + r0 * 8 + i;
        if (n < NN) {
            unsigned short* pT = &projT[(size_t)n * 128];
#pragma unroll
            for (int j = 0; j < 4; j++) pT[(f0 + j) * 8 + h] = f32_to_bf16_rne(acc[i][j]);
            // partial scores over this thread's 4 features, reduce across the 4
            // threads (lanes t, t^1, t^2) that share head h for this row
            float ss = acc[i][0] * aS0 + acc[i][1] * aS1 + acc[i][2] * aS2 + acc[i][3] * aS3;
            float st = acc[i][0] * aT0 + acc[i][1] * aT1 + acc[i][2] * aT2 + acc[i][3] * aT3;
            ss += __shfl_xor(ss, 1);
            ss += __shfl_xor(ss, 2);
            st += __shfl_xor(st, 1);
            st += __shfl_xor(st, 2);
            if ((t & 3) == 0) {
                s_src[(size_t)n * 8 + h] = ss;
                pack[(size_t)n * 16 + h] = st;   // s_tgt half of the packed line
            }
        }
    }
}

// ---------------- Kernel 2: per-(edge,head) exp(leaky) -> denom (segment sum) ----------------
// denom lives in pack[n*16 + 8 + h], same 64B line as s_tgt -> one line per node.
__global__ __launch_bounds__(256) void denom_kernel(const int* __restrict__ src,
                                                    const int* __restrict__ tgt,
                                                    const float* __restrict__ s_src,
                                                    float* __restrict__ pack) {
    int gid = blockIdx.x * blockDim.x + threadIdx.x;
    int e = gid >> 3;
    if (e >= NE) return;
    int h = gid & 7;
    int s = src[e], t = tgt[e];
    float v = s_src[(size_t)s * 8 + h] + pack[(size_t)t * 16 + h];
    v = v >= 0.f ? v : 0.2f * v;
    atomicAdd(&pack[(size_t)t * 16 + 8 + h], expf(v));
}

// ---------------- Kernel 3: per-edge alpha, head-reduced message, scatter-add ----------------
__global__ __launch_bounds__(256) void aggregate_kernel(const int* __restrict__ src,
                                                        const int* __restrict__ tgt,
                                                        const float* __restrict__ s_src,
                                                        const float* __restrict__ pack,
                                                        const unsigned short* __restrict__ projT,
                                                        float* __restrict__ out_acc) {
    int gid = blockIdx.x * blockDim.x + threadIdx.x;
    int e = gid >> 4;
    int lane = gid & 15;   // output feature f
    if (e >= NE) return;
    int s = src[e], t = tgt[e];
    int h = lane & 7;
    float eh = s_src[(size_t)s * 8 + h] + pack[(size_t)t * 16 + h];
    eh = eh >= 0.f ? eh : 0.2f * eh;
    float ex = expf(eh);
    float alpha = ex / (pack[(size_t)t * 16 + 8 + h] + 1e-16f);
    // gather 8 heads at feature 'lane': 16 bytes
    uint4 v = *reinterpret_cast<const uint4*>(&projT[(size_t)s * 128 + lane * 8]);
    float p0 = bf16_to_f32(v.x & 0xffffu), p1 = bf16_to_f32(v.x >> 16);
    float p2 = bf16_to_f32(v.y & 0xffffu), p3 = bf16_to_f32(v.y >> 16);
    float p4 = bf16_to_f32(v.z & 0xffffu), p5 = bf16_to_f32(v.z >> 16);
    float p6 = bf16_to_f32(v.w & 0xffffu), p7 = bf16_to_f32(v.w >> 16);
    float m = 0.f;
    m += __shfl(alpha, 0, 16) * p0;
    m += __shfl(alpha, 1, 16) * p1;
    m += __shfl(alpha, 2, 16) * p2;
    m += __shfl(alpha, 3, 16) * p3;
    m += __shfl(alpha, 4, 16) * p4;
    m += __shfl(alpha, 5, 16) * p5;
    m += __shfl(alpha, 6, 16) * p6;
    m += __shfl(alpha, 7, 16) * p7;
    atomicAdd(&out_acc[(size_t)t * 16 + lane], m * 0.125f);
}

// ---------------- Kernel 4: bias + softmax over 16 features ----------------
__global__ __launch_bounds__(256) void softmax_kernel(const float* __restrict__ out_acc,
                                                      const float* __restrict__ bias,
                                                      float* __restrict__ out) {
    int gid = blockIdx.x * blockDim.x + threadIdx.x;
    int n = gid >> 4;
    int lane = gid & 15;
    if (n >= NN) return;
    float v = out_acc[(size_t)n * 16 + lane] + bias[lane];
    float mx = v;
#pragma unroll
    for (int m = 1; m < 16; m <<= 1) mx = fmaxf(mx, __shfl_xor(mx, m, 64));
    float ex = expf(v - mx);
    float sum = ex;
#pragma unroll
    for (int m = 1; m < 16; m <<= 1) sum += __shfl_xor(sum, m, 64);
    out[(size_t)n * 16 + lane] = ex / sum;
}

extern "C" void kernel_launch(void* const* d_in, const int* in_sizes, int n_in,
                              void* d_out, int out_size, void* d_ws, size_t ws_size,
                              hipStream_t stream) {
    const float* x     = (const float*)d_in[0];
    const int*   ei    = (const int*)d_in[1];
    const float* W     = (const float*)d_in[2];
    const float* a_src = (const float*)d_in[3];
    const float* a_tgt = (const float*)d_in[4];
    const float* bias  = (const float*)d_in[5];
    float* out = (float*)d_out;

    const int* src = ei;            // edge_index[0]
    const int* tgt = ei + NE;       // edge_index[1]

    char* ws = (char*)d_ws;
    size_t off = 0;
    auto alloc = [&](size_t bytes) {
        char* p = ws + off;
        off += (bytes + 255) & ~(size_t)255;
        return p;
    };
    unsigned short* projT   = (unsigned short*)alloc((size_t)NN * 128 * 2); // 25.6 MB bf16, f-major
    float*          s_src   = (float*)alloc((size_t)NN * 8 * 4);            // 3.2 MB
    float*          pack    = (float*)alloc((size_t)NN * 16 * 4);           // 6.4 MB: [0..7]=s_tgt, [8..15]=denom
    float*          out_acc = (float*)alloc((size_t)NN * 16 * 4);           // 6.4 MB

    // zero accumulators every call (harness does not re-poison between replays)
    hipMemsetAsync(pack, 0, (size_t)NN * 16 * 4, stream);
    hipMemsetAsync(out_acc, 0, (size_t)NN * 16 * 4, stream);

    gemm_score_kernel<<<(NN + 63) / 64, 256, 0, stream>>>(x, W, a_src, a_tgt, projT, s_src, pack);
    denom_kernel<<<((size_t)NE * 8 + 255) / 256, 256, 0, stream>>>(src, tgt, s_src, pack);
    aggregate_kernel<<<((size_t)NE * 16 + 255) / 256, 256, 0, stream>>>(src, tgt, s_src, pack,
                                                                        projT, out_acc);
    softmax_kernel<<<(NN * 16 + 255) / 256, 256, 0, stream>>>(out_acc, bias, out);
}